// Round 2
// baseline (2093.070 us; speedup 1.0000x reference)
//
#include <hip/hip_runtime.h>

#define DD 12
#define VOX 1728
#define BN_EPS 1e-5f
#define BATCH 512
#define PER 864
#define PERZ 865                                  // PER + 1 zero row per batch

typedef __attribute__((ext_vector_type(8))) short short8;   // 8 bf16 = 16B
typedef __attribute__((ext_vector_type(4))) float f32x4;
typedef unsigned short u16;

__device__ inline u16 f2b(float f) {              // fp32 -> bf16 RNE
    union { float f; unsigned u; } v; v.f = f;
    unsigned r = v.u + 0x7fffu + ((v.u >> 16) & 1u);
    return (u16)(r >> 16);
}
__device__ inline float b2f(u16 h) {
    union { unsigned u; float f; } v; v.u = ((unsigned)h) << 16;
    return v.f;
}
constexpr int ilog2(int v) { return v == 1 ? 0 : 1 + ilog2(v / 2); }

__device__ __forceinline__ void async_copy16(const void* g, void* l) {
    __builtin_amdgcn_global_load_lds(
        (const __attribute__((address_space(1))) void*)g,
        (__attribute__((address_space(3))) void*)l, 16, 0, 0);
}

// counted vmcnt wait; memory clobber pins memory-op motion across it
template<int N> __device__ __forceinline__ void wait_vm() {
    if constexpr (N == 0)       asm volatile("s_waitcnt vmcnt(0)"  ::: "memory");
    else if constexpr (N == 10) asm volatile("s_waitcnt vmcnt(10)" ::: "memory");
    else if constexpr (N == 12) asm volatile("s_waitcnt vmcnt(12)" ::: "memory");
    else if constexpr (N == 14) asm volatile("s_waitcnt vmcnt(14)" ::: "memory");
    else if constexpr (N == 16) asm volatile("s_waitcnt vmcnt(16)" ::: "memory");
    else if constexpr (N == 18) asm volatile("s_waitcnt vmcnt(18)" ::: "memory");
    else static_assert(N == 0, "unhandled vmcnt value");
}

// ---------------- voxel -> point-row map ----------------
__global__ void build_map_kernel(const int* __restrict__ idx, int* __restrict__ map, int N) {
    int p = blockIdx.x * blockDim.x + threadIdx.x;
    if (p >= N) return;
    const int4 v = ((const int4*)idx)[p];
    map[v.x * VOX + (v.y * DD + v.z) * DD + v.w] = p;
}

// ---------------- neighbor table: local row in batch, PER = zero-row sentinel ----------------
__global__ void build_nbr_kernel(const int* __restrict__ idx, const int* __restrict__ map,
                                 u16* __restrict__ nbr, int N) {
    int t = blockIdx.x * blockDim.x + threadIdx.x;
    int p = t >> 5, nk = t & 31;
    if (p >= N) return;
    u16 out = PER;
    if (nk < 27) {
        const int4 v = ((const int4*)idx)[p];
        int dz = nk / 9 - 1, dy = (nk / 3) % 3 - 1, dx = nk % 3 - 1;
        int zz = v.y + dz, yy = v.z + dy, xx = v.w + dx;
        if (zz >= 0 && zz < DD && yy >= 0 && yy < DD && xx >= 0 && xx < DD) {
            int q = map[v.x * VOX + (zz * DD + yy) * DD + xx];
            if (q >= 0) out = (u16)(q - v.x * PER);
        }
    }
    nbr[t] = out;
}

// ---------------- W [K][COUT] fp32 -> Wt [COUT][Kpad] bf16 (pad pre-zeroed) ----------------
__global__ void transpose_w_kernel(const float* __restrict__ W, u16* __restrict__ Wt,
                                   int K, int COUT, int Kpad) {
    int i = blockIdx.x * blockDim.x + threadIdx.x;
    if (i >= K * COUT) return;
    int n = i % COUT, k = i / COUT;
    Wt[(size_t)n * Kpad + k] = f2b(W[i]);
}

// ---------------- zero the per-batch zero rows of a feature buffer ----------------
__global__ void zero_rows_kernel(u16* __restrict__ f, int CIN) {
    int t = blockIdx.x * blockDim.x + threadIdx.x;          // over BATCH*CIN/4
    int e4 = CIN >> 2;
    if (t >= BATCH * e4) return;
    int b = t / e4, k = t - b * e4;
    ((ushort4*)f)[(size_t)(b * PERZ + PER) * e4 + k] = make_ushort4(0, 0, 0, 0);
}

// ---------------- fp32 feats -> bf16, strided (PERZ) layout ----------------
__global__ void cast_bf16_kernel(const float* __restrict__ in, u16* __restrict__ out, int N4) {
    int i = blockIdx.x * blockDim.x + threadIdx.x;          // over N*4 (float4 groups, CIN=16)
    if (i >= N4) return;
    float4 v = ((const float4*)in)[i];
    int p = i >> 2, c4 = i & 3;
    int b = p / PER, r = p - b * PER;
    ushort4 o;
    o.x = f2b(v.x); o.y = f2b(v.y); o.z = f2b(v.z); o.w = f2b(v.w);
    ((ushort4*)out)[(size_t)(b * PERZ + r) * 4 + c4] = o;
}

// ---------------- implicit-GEMM conv: A gathered direct to registers, B staged in LDS ----
// A-fragment gather: lane (lr,lq) of wave wm, row-frag i, k-half sh reads 16B of row
// p0+wm*64+i*16+lr at k = kb*64+sh*32+lq*8 -> exactly the mfma_16x16x32 A layout.
// A frags + neighbor ids double-buffered in regs (prefetch dist 1); B double-buffered
// in LDS via swizzled global_load_lds. Counted vmcnt keeps next-step loads in flight
// across raw s_barrier (never drain to 0 mid-loop).
template<int CIN, int COUT, int BM, int WM, int WN>
__global__ __launch_bounds__(256) void conv_mfma_kernel(
    const u16* __restrict__ fin,      // (BATCH*PERZ) x CIN bf16 (zero row per batch)
    const u16* __restrict__ nbr,      // N x 32 u16
    const u16* __restrict__ Wt,       // COUT x Kpad bf16
    const float* __restrict__ bias,
    float* __restrict__ y,
    float* __restrict__ stats) {
    constexpr int Kpad   = (27 * CIN + 63) & ~63;
    constexpr int KSTEPS = Kpad / 64;
    constexpr int BN     = WN * 64;
    constexpr int BSLOTS = BN / 32;               // per-thread 16B DMA slots for B
    constexpr int NS     = (CIN == 16) ? 2 : 1;   // q values per row per step
    constexpr int NQ     = 4 * NS;                // q loads per step
    constexpr int BUFB   = BN * 128;              // one B buffer (BN rows x 128B)
    static_assert(KSTEPS >= 3, "pipeline prologue needs >=3 K-steps");
    __shared__ char smem[2 * BUFB];               // B double-buffer only

    // XCD-contiguous swizzle
    const int perx = gridDim.x >> 3;
    const int bid = (blockIdx.x & 7) * perx + (blockIdx.x >> 3);
    const int p0 = bid * BM;

    const int tid = threadIdx.x;
    const int wave = tid >> 6, lane = tid & 63;
    const int wm = wave / WN, wn = wave % WN;     // 64x64 wave tile at (wm*64, wn*64)
    const int lq = lane >> 4, lr = lane & 15;
    const int lrow = lane >> 3;                   // DMA row within 8-row group (B staging)
    const int kc_d = (lane & 7) ^ (lrow & 7);     // swizzled chunk this lane fetches (B)

    // ---- B staging invariants ----
    int bvoff[BSLOTS];
    #pragma unroll
    for (int j = 0; j < BSLOTS; j++)
        bvoff[j] = ((wave * BSLOTS + j) * 8 + lrow) * Kpad + kc_d * 8;

    // B fragment read addrs: physical chunk = logical ^ (row&7)
    int phs[2];
    phs[0] = ((0 + lq) ^ (lr & 7)) * 16;
    phs[1] = ((4 + lq) ^ (lr & 7)) * 16;
    const int bBase = (wn * 64 + lr) * 128;

    // ---- A row invariants: 4 row-frags per wave ----
    const char* nbrB = (const char*)nbr;
    const char* finB = (const char*)fin;
    int nbq[4], abase[4];
    #pragma unroll
    for (int i = 0; i < 4; i++) {
        int p = p0 + wm * 64 + i * 16 + lr;
        int b = p / PER;
        nbq[i]   = p * 64;                        // bytes into nbr
        abase[i] = b * PERZ * CIN * 2;            // bytes into fin (batch base)
    }

    const f32x4 fzero = {0.f, 0.f, 0.f, 0.f};
    f32x4 acc[4][4];
    #pragma unroll
    for (int i = 0; i < 4; i++)
        #pragma unroll
        for (int j = 0; j < 4; j++) acc[i][j] = fzero;

    u16 qX[4][NS], qY[4][NS];
    short8 aX[8], aY[8];

    auto loadQ = [&](int s, u16 (&qq)[4][NS]) {
        #pragma unroll
        for (int i = 0; i < 4; i++)
            #pragma unroll
            for (int ns = 0; ns < NS; ns++) {
                int tap;
                if constexpr (CIN == 16)       tap = s * 4 + ns * 2 + (lq >> 1);
                else if constexpr (CIN == 64)  tap = s;
                else                           tap = s >> 1;
                qq[i][ns] = *(const u16*)(nbrB + nbq[i] + tap * 2);
            }
    };
    auto issueA = [&](int s, short8 (&aa)[8], u16 (&qq)[4][NS]) {
        #pragma unroll
        for (int i = 0; i < 4; i++)
            #pragma unroll
            for (int sh = 0; sh < 2; sh++) {
                int ch;
                if constexpr (CIN == 16)       ch = (lq & 1) * 8;
                else if constexpr (CIN == 64)  ch = sh * 32 + lq * 8;
                else                           ch = (s & 1) * 64 + sh * 32 + lq * 8;
                int q = (NS == 2) ? (int)qq[i][sh] : (int)qq[i][0];
                aa[i * 2 + sh] = *(const short8*)(finB + abase[i] + q * (CIN * 2) + ch * 2);
            }
    };
    auto stageB = [&](int s, int so) {
        const u16* wsrc = Wt + s * 64;
        #pragma unroll
        for (int j = 0; j < BSLOTS; j++)
            async_copy16(wsrc + bvoff[j], smem + so + (wave * BSLOTS + j) * 1024);
    };
    auto compute = [&](short8 (&aa)[8], int so) {
        #pragma unroll
        for (int sh = 0; sh < 2; sh++) {
            short8 bfr[4];
            #pragma unroll
            for (int j = 0; j < 4; j++)
                bfr[j] = *(const short8*)(smem + so + bBase + j * 2048 + phs[sh]);
            #pragma unroll
            for (int i = 0; i < 4; i++)
                #pragma unroll
                for (int j = 0; j < 4; j++)
                    acc[i][j] = __builtin_amdgcn_mfma_f32_16x16x32_bf16(aa[i * 2 + sh], bfr[j], acc[i][j], 0, 0, 0);
        }
    };

    // step body: prefetch (k+1) B->LDS + A->regs, prefetch q(k+2), counted wait, compute(k)
    auto step_body = [&](int k, short8 (&aC)[8], short8 (&aN)[8],
                         u16 (&qI)[4][NS], u16 (&qL)[4][NS], int soC, int soN) {
        const bool haveNext = (k + 1 < KSTEPS);
        const bool haveQ    = (k + 2 < KSTEPS);
        if (haveNext) {
            stageB(k + 1, soN);
            issueA(k + 1, aN, qI);                // qI loaded >=1 step ago
        }
        if (haveQ) loadQ(k + 2, qL);
        if (haveNext) {
            if (haveQ) wait_vm<BSLOTS + 8 + NQ>();   // leave this step's issues in flight
            else       wait_vm<BSLOTS + 8>();
        } else {
            wait_vm<0>();
        }
        __builtin_amdgcn_s_barrier();             // B(k) landed block-wide
        compute(aC, soC);
        asm volatile("s_waitcnt lgkmcnt(0)" ::: "memory");
        __builtin_amdgcn_s_barrier();             // B buf free for overwrite
    };

    // ---- pipeline prologue ----
    loadQ(0, qX);
    issueA(0, aX, qX);                            // one-time serialized q->A in prologue
    stageB(0, 0);
    loadQ(1, qY);

    #pragma unroll 1
    for (int kb = 0; kb < KSTEPS; kb += 2) {
        step_body(kb, aX, aY, qY, qX, 0, BUFB);
        if (kb + 1 < KSTEPS)
            step_body(kb + 1, aY, aX, qX, qY, BUFB, 0);
    }

    // ---- epilogue: bias, store y, fused per-channel sum/sumsq ----
    #pragma unroll
    for (int j = 0; j < 4; j++) {
        int col = wn * 64 + j * 16 + lr;
        float bv = bias[col];
        float s = 0.f, s2 = 0.f;
        #pragma unroll
        for (int i = 0; i < 4; i++) {
            int row0 = p0 + wm * 64 + i * 16 + lq * 4;
            #pragma unroll
            for (int r = 0; r < 4; r++) {
                float v = acc[i][j][r] + bv;
                y[(size_t)(row0 + r) * COUT + col] = v;
                s += v; s2 += v * v;
            }
        }
        s  += __shfl_down(s, 32);  s  += __shfl_down(s, 16);
        s2 += __shfl_down(s2, 32); s2 += __shfl_down(s2, 16);
        if (lane < 16) {
            atomicAdd(&stats[col], s);
            atomicAdd(&stats[COUT + col], s2);
        }
    }
}

// ---------------- fold BN into scale/shift ----------------
template<int COUT>
__global__ void finalize_kernel(const float* __restrict__ stats, const float* __restrict__ gamma,
                                const float* __restrict__ beta, float* __restrict__ ss, int N) {
    int co = threadIdx.x;
    float inv_n = 1.f / (float)N;
    float mu  = stats[co] * inv_n;
    float var = stats[COUT + co] * inv_n - mu * mu;
    float sc  = gamma[co] * rsqrtf(var + BN_EPS);
    ss[co]        = sc;
    ss[COUT + co] = beta[co] - mu * sc;
}

// ---------------- BN + ReLU, emit bf16 into strided (PERZ) layout ----------------
template<int COUT>
__global__ void apply_kernel(const float* __restrict__ y, const float* __restrict__ ss,
                             u16* __restrict__ f, int total4) {
    int i = blockIdx.x * blockDim.x + threadIdx.x;
    if (i >= total4) return;
    constexpr int E4 = COUT / 4;
    float4 v = ((const float4*)y)[i];
    int p = i / E4, k = i - p * E4;
    int c0 = k * 4;
    int b = p / PER, r = p - b * PER;
    ushort4 o;
    float a;
    a = fmaf(v.x, ss[c0 + 0], ss[COUT + c0 + 0]); o.x = f2b(a > 0.f ? a : 0.f);
    a = fmaf(v.y, ss[c0 + 1], ss[COUT + c0 + 1]); o.y = f2b(a > 0.f ? a : 0.f);
    a = fmaf(v.z, ss[c0 + 2], ss[COUT + c0 + 2]); o.z = f2b(a > 0.f ? a : 0.f);
    a = fmaf(v.w, ss[c0 + 3], ss[COUT + c0 + 3]); o.w = f2b(a > 0.f ? a : 0.f);
    ((ushort4*)f)[(size_t)(b * PERZ + r) * E4 + k] = o;
}

// ---------------- dense NCDHW output ----------------
__global__ void output_kernel(const u16* __restrict__ f, const int* __restrict__ map,
                              float* __restrict__ out, int total) {
    int i = blockIdx.x * blockDim.x + threadIdx.x;
    if (i >= total) return;
    int voxel = i % VOX;
    int bc    = i / VOX;
    int c = bc & 63;
    int b = bc >> 6;
    int p = map[b * VOX + voxel];
    float v = 0.f;
    if (p >= 0) {
        int r = p - b * PER;
        v = b2f(f[(size_t)(b * PERZ + r) * 64 + c]);
    }
    out[i] = v;
}

extern "C" void kernel_launch(void* const* d_in, const int* in_sizes, int n_in,
                              void* d_out, int out_size, void* d_ws, size_t ws_size,
                              hipStream_t stream) {
    const float* feats = (const float*)d_in[0];
    const int*   idx   = (const int*)  d_in[1];
    const float* W0 = (const float*)d_in[3];
    const float* b0 = (const float*)d_in[4];
    const float* g0 = (const float*)d_in[5];
    const float* e0 = (const float*)d_in[6];
    const float* W1 = (const float*)d_in[7];
    const float* b1 = (const float*)d_in[8];
    const float* g1 = (const float*)d_in[9];
    const float* e1 = (const float*)d_in[10];
    const float* W2 = (const float*)d_in[11];
    const float* b2 = (const float*)d_in[12];
    const float* g2 = (const float*)d_in[13];
    const float* e2 = (const float*)d_in[14];

    const int N = in_sizes[0] / 16;               // 442368

    // ---- workspace layout ----
    char* ws = (char*)d_ws;
    size_t off = 0;
    auto alloc = [&](size_t bytes) { void* p = ws + off; off = (off + bytes + 255) & ~(size_t)255; return p; };
    int*   map   = (int*)  alloc((size_t)BATCH * VOX * 4);
    float* stats = (float*)alloc(3 * 256 * 4);
    float* ss    = (float*)alloc(3 * 256 * 4);
    u16*   nbr   = (u16*)  alloc((size_t)N * 32 * 2);
    u16*   wt0   = (u16*)  alloc((size_t)64  * 448  * 2);
    u16*   wt1   = (u16*)  alloc((size_t)128 * 1728 * 2);
    u16*   wt2   = (u16*)  alloc((size_t)64  * 3456 * 2);
    u16*   fbuf  = (u16*)  alloc((size_t)BATCH * PERZ * 128 * 2);   // shared by all layers
    float* y = (float*)d_out;                     // fp32 conv out, aliases d_out

    hipMemsetAsync(map,   0xFF, (size_t)BATCH * VOX * 4, stream);
    hipMemsetAsync(stats, 0,    3 * 256 * 4, stream);
    hipMemsetAsync(wt0,   0,    (size_t)64 * 448 * 2, stream);      // zero K-pad
    build_map_kernel<<<(N + 255) / 256, 256, 0, stream>>>(idx, map, N);
    build_nbr_kernel<<<(N * 32 + 255) / 256, 256, 0, stream>>>(idx, map, nbr, N);
    transpose_w_kernel<<<(432  * 64  + 255) / 256, 256, 0, stream>>>(W0, wt0, 432,  64,  448);
    transpose_w_kernel<<<(1728 * 128 + 255) / 256, 256, 0, stream>>>(W1, wt1, 1728, 128, 1728);
    transpose_w_kernel<<<(3456 * 64  + 255) / 256, 256, 0, stream>>>(W2, wt2, 3456, 64,  3456);

    // ---- layer 1: 16 -> 64 (BM=256, waves 4x1) ----
    zero_rows_kernel<<<(BATCH * 4 + 255) / 256, 256, 0, stream>>>(fbuf, 16);
    cast_bf16_kernel<<<(N * 4 + 255) / 256, 256, 0, stream>>>(feats, fbuf, N * 4);
    conv_mfma_kernel<16, 64, 256, 4, 1><<<N / 256, 256, 0, stream>>>(fbuf, nbr, wt0, b0, y, stats + 0);
    finalize_kernel<64><<<1, 64, 0, stream>>>(stats + 0, g0, e0, ss + 0, N);
    zero_rows_kernel<<<(BATCH * 16 + 255) / 256, 256, 0, stream>>>(fbuf, 64);
    apply_kernel<64><<<(N * 16 + 255) / 256, 256, 0, stream>>>(y, ss + 0, fbuf, N * 16);

    // ---- layer 2: 64 -> 128 (BM=128, waves 2x2) ----
    conv_mfma_kernel<64, 128, 128, 2, 2><<<N / 128, 256, 0, stream>>>(fbuf, nbr, wt1, b1, y, stats + 256);
    finalize_kernel<128><<<1, 128, 0, stream>>>(stats + 256, g1, e1, ss + 256, N);
    zero_rows_kernel<<<(BATCH * 32 + 255) / 256, 256, 0, stream>>>(fbuf, 128);
    apply_kernel<128><<<(N * 32 + 255) / 256, 256, 0, stream>>>(y, ss + 256, fbuf, N * 32);

    // ---- layer 3: 128 -> 64 (BM=256, waves 4x1) ----
    conv_mfma_kernel<128, 64, 256, 4, 1><<<N / 256, 256, 0, stream>>>(fbuf, nbr, wt2, b2, y, stats + 512);
    finalize_kernel<64><<<1, 64, 0, stream>>>(stats + 512, g2, e2, ss + 512, N);
    zero_rows_kernel<<<(BATCH * 16 + 255) / 256, 256, 0, stream>>>(fbuf, 64);
    apply_kernel<64><<<(N * 16 + 255) / 256, 256, 0, stream>>>(y, ss + 512, fbuf, N * 16);

    // ---- dense NCDHW output ----
    output_kernel<<<(out_size + 255) / 256, 256, 0, stream>>>(fbuf, map, (float*)d_out, out_size);
}

// Round 3
// 1357.590 us; speedup vs baseline: 1.5418x; 1.5418x over previous
//
#include <hip/hip_runtime.h>

#define DD 12
#define VOX 1728
#define BN_EPS 1e-5f
#define BATCH 512
#define PER 864
#define PERZ 865                                  // PER + 1 zero row per batch
#define NTOT (BATCH * PER)                        // 442368 points

typedef __attribute__((ext_vector_type(8))) short short8;   // 8 bf16 = 16B
typedef __attribute__((ext_vector_type(4))) float f32x4;
typedef unsigned short u16;

__device__ inline u16 f2b(float f) {              // fp32 -> bf16 RNE
    union { float f; unsigned u; } v; v.f = f;
    unsigned r = v.u + 0x7fffu + ((v.u >> 16) & 1u);
    return (u16)(r >> 16);
}
__device__ inline float b2f(u16 h) {
    union { unsigned u; float f; } v; v.u = ((unsigned)h) << 16;
    return v.f;
}
constexpr int ilog2(int v) { return v == 1 ? 0 : 1 + ilog2(v / 2); }

__device__ __forceinline__ void async_copy16(const void* g, void* l) {
    __builtin_amdgcn_global_load_lds(
        (const __attribute__((address_space(1))) void*)g,
        (__attribute__((address_space(3))) void*)l, 16, 0, 0);
}

// counted vmcnt wait; memory clobber pins memory-op motion across it
template<int N> __device__ __forceinline__ void wait_vm() {
    if constexpr (N == 0)       asm volatile("s_waitcnt vmcnt(0)"  ::: "memory");
    else if constexpr (N == 8)  asm volatile("s_waitcnt vmcnt(8)"  ::: "memory");
    else if constexpr (N == 10) asm volatile("s_waitcnt vmcnt(10)" ::: "memory");
    else if constexpr (N == 12) asm volatile("s_waitcnt vmcnt(12)" ::: "memory");
    else if constexpr (N == 18) asm volatile("s_waitcnt vmcnt(18)" ::: "memory");
    else static_assert(N == 0, "unhandled vmcnt value");
}

// ---------------- voxel -> point-row map ----------------
__global__ void build_map_kernel(const int* __restrict__ idx, int* __restrict__ map, int N) {
    int p = blockIdx.x * blockDim.x + threadIdx.x;
    if (p >= N) return;
    const int4 v = ((const int4*)idx)[p];
    map[v.x * VOX + (v.y * DD + v.z) * DD + v.w] = p;
}

// ---------------- neighbor table, TAP-MAJOR: nbr[tap][point] ----------------
// Per-step q loads in the conv kernel read 8 consecutive points at a uniform tap
// -> 1-2 cache lines per instruction instead of 16 (point-major was 2B strided 64B).
__global__ void build_nbr_kernel(const int* __restrict__ idx, const int* __restrict__ map,
                                 u16* __restrict__ nbr, int N) {
    int p = blockIdx.x * blockDim.x + threadIdx.x;
    if (p >= N) return;
    const int4 v = ((const int4*)idx)[p];
    const int base = v.x * VOX;
    const int lb = v.x * PER;
    #pragma unroll
    for (int nk = 0; nk < 27; nk++) {
        int dz = nk / 9 - 1, dy = (nk / 3) % 3 - 1, dx = nk % 3 - 1;
        int zz = v.y + dz, yy = v.z + dy, xx = v.w + dx;
        u16 out = PER;
        if (zz >= 0 && zz < DD && yy >= 0 && yy < DD && xx >= 0 && xx < DD) {
            int q = map[base + (zz * DD + yy) * DD + xx];
            if (q >= 0) out = (u16)(q - lb);
        }
        nbr[nk * N + p] = out;
    }
    #pragma unroll
    for (int nk = 27; nk < 32; nk++) nbr[nk * N + p] = PER;
}

// ---------------- W [K][COUT] fp32 -> Wt [COUT][Kpad] bf16 (pad pre-zeroed) ----------------
__global__ void transpose_w_kernel(const float* __restrict__ W, u16* __restrict__ Wt,
                                   int K, int COUT, int Kpad) {
    int i = blockIdx.x * blockDim.x + threadIdx.x;
    if (i >= K * COUT) return;
    int n = i % COUT, k = i / COUT;
    Wt[(size_t)n * Kpad + k] = f2b(W[i]);
}

// ---------------- zero the per-batch zero rows of a feature buffer ----------------
__global__ void zero_rows_kernel(u16* __restrict__ f, int CIN) {
    int t = blockIdx.x * blockDim.x + threadIdx.x;          // over BATCH*CIN/4
    int e4 = CIN >> 2;
    if (t >= BATCH * e4) return;
    int b = t / e4, k = t - b * e4;
    ((ushort4*)f)[(size_t)(b * PERZ + PER) * e4 + k] = make_ushort4(0, 0, 0, 0);
}

// ---------------- fp32 feats -> bf16, strided (PERZ) layout ----------------
__global__ void cast_bf16_kernel(const float* __restrict__ in, u16* __restrict__ out, int N4) {
    int i = blockIdx.x * blockDim.x + threadIdx.x;          // over N*4 (float4 groups, CIN=16)
    if (i >= N4) return;
    float4 v = ((const float4*)in)[i];
    int p = i >> 2, c4 = i & 3;
    int b = p / PER, r = p - b * PER;
    ushort4 o;
    o.x = f2b(v.x); o.y = f2b(v.y); o.z = f2b(v.z); o.w = f2b(v.w);
    ((ushort4*)out)[(size_t)(b * PERZ + r) * 4 + c4] = o;
}

// ---------------- implicit-GEMM conv: double-buffered async-DMA 2-phase K-loop ----------------
// Wave tile 64x64 (acc 4x4), BK=64. stage(kb+1) overlaps compute(kb):
//   stage->buf^1 ; loadQ ; s_waitcnt vmcnt(counted) ; raw barrier ; compute buf ; raw barrier
// Raw s_barrier (NOT __syncthreads) so the prefetch stays in flight across the barrier.
// nbr is tap-major: q-load addr = tap*NTOT*2 + p*2 (coalesced across the 8-row group).
template<int CIN, int COUT, int BM, int WM, int WN>
__global__ __launch_bounds__(256) void conv_mfma_kernel(
    const u16* __restrict__ fin,      // (BATCH*PERZ) x CIN bf16 (zero row per batch)
    const u16* __restrict__ nbr,      // 32 x NTOT u16 (tap-major)
    const u16* __restrict__ Wt,       // COUT x Kpad bf16
    const float* __restrict__ bias,
    float* __restrict__ y,
    float* __restrict__ stats) {
    constexpr int Kpad   = (27 * CIN + 63) & ~63;
    constexpr int KSTEPS = Kpad / 64;
    constexpr int L2C    = ilog2(CIN);
    constexpr int BN     = WN * 64;
    constexpr int ASLOTS = BM / 32;               // per-thread 16B DMA slots for A
    constexpr int BSLOTS = BN / 32;
    constexpr int A_OFF  = BN * 128;              // sB first, then sA (within a buffer)
    constexpr int BUFB   = (BM + BN) * 128;       // one buffer
    static_assert(KSTEPS >= 3, "pipeline prologue needs >=3 K-steps");
    __shared__ char smem[2 * BUFB];               // double-buffered

    // XCD-contiguous swizzle
    const int perx = gridDim.x >> 3;
    const int bid = (blockIdx.x & 7) * perx + (blockIdx.x >> 3);
    const int p0 = bid * BM;

    const int tid = threadIdx.x;
    const int wave = tid >> 6, lane = tid & 63;
    const int wm = wave / WN, wn = wave % WN;     // 64x64 wave tile at (wm*64, wn*64)
    const int lq = lane >> 4, lr = lane & 15;
    const int lrow = lane >> 3;                   // DMA row within 8-row group
    const int kc_d = (lane & 7) ^ (lrow & 7);     // swizzled chunk this lane fetches

    // ---- per-slot invariants ----
    int qvoff[ASLOTS], gbase[ASLOTS];
    #pragma unroll
    for (int i = 0; i < ASLOTS; i++) {
        int m = (wave * ASLOTS + i) * 8 + lrow;
        int p = p0 + m;
        int b = p / PER;
        qvoff[i] = (((kc_d * 8) >> L2C) * NTOT + p) * 2;        // bytes into tap-major nbr
        gbase[i] = b * PERZ * CIN + ((kc_d * 8) & (CIN - 1));   // elems into fin
    }
    int bvoff[BSLOTS];
    #pragma unroll
    for (int j = 0; j < BSLOTS; j++)
        bvoff[j] = ((wave * BSLOTS + j) * 8 + lrow) * Kpad + kc_d * 8;

    // fragment read addrs: physical chunk = logical ^ (row&7)
    int phs[2];
    phs[0] = ((0 + lq) ^ (lr & 7)) * 16;
    phs[1] = ((4 + lq) ^ (lr & 7)) * 16;
    const int aBase = A_OFF + (wm * 64 + lr) * 128;
    const int bBase = (wn * 64 + lr) * 128;

    const f32x4 fzero = {0.f, 0.f, 0.f, 0.f};
    f32x4 acc[4][4];
    #pragma unroll
    for (int i = 0; i < 4; i++)
        #pragma unroll
        for (int j = 0; j < 4; j++) acc[i][j] = fzero;

    u16 q[ASLOTS];
    auto loadQ = [&](int step) {
        int sQ = ((step * 64) >> L2C) * (NTOT * 2);             // tap-major stride
        #pragma unroll
        for (int i = 0; i < ASLOTS; i++)
            q[i] = *(const u16*)((const char*)nbr + qvoff[i] + sQ);
    };
    auto stage = [&](int step, int bo) {
        int sG = (step * 64) & (CIN - 1);
        const u16* fs = fin + sG;
        #pragma unroll
        for (int i = 0; i < ASLOTS; i++)
            async_copy16(fs + gbase[i] + ((int)q[i] << L2C),
                         smem + bo + A_OFF + (wave * ASLOTS + i) * 1024);
        const u16* wsrc = Wt + step * 64;
        #pragma unroll
        for (int j = 0; j < BSLOTS; j++)
            async_copy16(wsrc + bvoff[j], smem + bo + (wave * BSLOTS + j) * 1024);
    };

    // ---- pipeline prologue ----
    loadQ(0);
    stage(0, 0);                                  // buf0 <- step 0
    loadQ(1);                                     // ids for step 1 (in flight)

    #pragma unroll 1
    for (int kb = 0; kb < KSTEPS; kb++) {
        // issue next-step prefetch into the other buffer, then wait (counted) for
        // THIS step's tile; the prefetch stays in flight across the barrier.
        if (kb + 1 < KSTEPS) {
            stage(kb + 1, ((kb + 1) & 1) * BUFB); // q-dep drains stage(kb) implicitly
            if (kb + 2 < KSTEPS) {
                loadQ(kb + 2);
                wait_vm<2 * ASLOTS + BSLOTS>();   // leave stage(kb+1)+loadQ in flight
            } else {
                wait_vm<ASLOTS + BSLOTS>();       // leave stage(kb+1) in flight
            }
        } else {
            wait_vm<0>();                         // last step: drain its tile
        }
        __builtin_amdgcn_s_barrier();             // all waves' tile(kb) landed

        const int so = (kb & 1) * BUFB;
        #pragma unroll
        for (int s = 0; s < 2; s++) {
            short8 af[4], bfr[4];
            #pragma unroll
            for (int i = 0; i < 4; i++)
                af[i] = *(const short8*)(smem + so + aBase + i * 2048 + phs[s]);
            #pragma unroll
            for (int j = 0; j < 4; j++)
                bfr[j] = *(const short8*)(smem + so + bBase + j * 2048 + phs[s]);
            #pragma unroll
            for (int i = 0; i < 4; i++)
                #pragma unroll
                for (int j = 0; j < 4; j++)
                    acc[i][j] = __builtin_amdgcn_mfma_f32_16x16x32_bf16(af[i], bfr[j], acc[i][j], 0, 0, 0);
        }
        asm volatile("s_waitcnt lgkmcnt(0)" ::: "memory");  // all ds_reads retired
        __builtin_amdgcn_s_barrier();             // before buf[kb&1] is overwritten
    }

    // ---- epilogue: bias, store y, fused per-channel sum/sumsq ----
    #pragma unroll
    for (int j = 0; j < 4; j++) {
        int col = wn * 64 + j * 16 + lr;
        float bv = bias[col];
        float s = 0.f, s2 = 0.f;
        #pragma unroll
        for (int i = 0; i < 4; i++) {
            int row0 = p0 + wm * 64 + i * 16 + lq * 4;
            #pragma unroll
            for (int r = 0; r < 4; r++) {
                float v = acc[i][j][r] + bv;
                y[(size_t)(row0 + r) * COUT + col] = v;
                s += v; s2 += v * v;
            }
        }
        s  += __shfl_down(s, 32);  s  += __shfl_down(s, 16);
        s2 += __shfl_down(s2, 32); s2 += __shfl_down(s2, 16);
        if (lane < 16) {
            atomicAdd(&stats[col], s);
            atomicAdd(&stats[COUT + col], s2);
        }
    }
}

// ---------------- fold BN into scale/shift ----------------
template<int COUT>
__global__ void finalize_kernel(const float* __restrict__ stats, const float* __restrict__ gamma,
                                const float* __restrict__ beta, float* __restrict__ ss, int N) {
    int co = threadIdx.x;
    float inv_n = 1.f / (float)N;
    float mu  = stats[co] * inv_n;
    float var = stats[COUT + co] * inv_n - mu * mu;
    float sc  = gamma[co] * rsqrtf(var + BN_EPS);
    ss[co]        = sc;
    ss[COUT + co] = beta[co] - mu * sc;
}

// ---------------- BN + ReLU, emit bf16 into strided (PERZ) layout ----------------
template<int COUT>
__global__ void apply_kernel(const float* __restrict__ y, const float* __restrict__ ss,
                             u16* __restrict__ f, int total4) {
    int i = blockIdx.x * blockDim.x + threadIdx.x;
    if (i >= total4) return;
    constexpr int E4 = COUT / 4;
    float4 v = ((const float4*)y)[i];
    int p = i / E4, k = i - p * E4;
    int c0 = k * 4;
    int b = p / PER, r = p - b * PER;
    ushort4 o;
    float a;
    a = fmaf(v.x, ss[c0 + 0], ss[COUT + c0 + 0]); o.x = f2b(a > 0.f ? a : 0.f);
    a = fmaf(v.y, ss[c0 + 1], ss[COUT + c0 + 1]); o.y = f2b(a > 0.f ? a : 0.f);
    a = fmaf(v.z, ss[c0 + 2], ss[COUT + c0 + 2]); o.z = f2b(a > 0.f ? a : 0.f);
    a = fmaf(v.w, ss[c0 + 3], ss[COUT + c0 + 3]); o.w = f2b(a > 0.f ? a : 0.f);
    ((ushort4*)f)[(size_t)(b * PERZ + r) * E4 + k] = o;
}

// ---------------- dense NCDHW output ----------------
__global__ void output_kernel(const u16* __restrict__ f, const int* __restrict__ map,
                              float* __restrict__ out, int total) {
    int i = blockIdx.x * blockDim.x + threadIdx.x;
    if (i >= total) return;
    int voxel = i % VOX;
    int bc    = i / VOX;
    int c = bc & 63;
    int b = bc >> 6;
    int p = map[b * VOX + voxel];
    float v = 0.f;
    if (p >= 0) {
        int r = p - b * PER;
        v = b2f(f[(size_t)(b * PERZ + r) * 64 + c]);
    }
    out[i] = v;
}

extern "C" void kernel_launch(void* const* d_in, const int* in_sizes, int n_in,
                              void* d_out, int out_size, void* d_ws, size_t ws_size,
                              hipStream_t stream) {
    const float* feats = (const float*)d_in[0];
    const int*   idx   = (const int*)  d_in[1];
    const float* W0 = (const float*)d_in[3];
    const float* b0 = (const float*)d_in[4];
    const float* g0 = (const float*)d_in[5];
    const float* e0 = (const float*)d_in[6];
    const float* W1 = (const float*)d_in[7];
    const float* b1 = (const float*)d_in[8];
    const float* g1 = (const float*)d_in[9];
    const float* e1 = (const float*)d_in[10];
    const float* W2 = (const float*)d_in[11];
    const float* b2 = (const float*)d_in[12];
    const float* g2 = (const float*)d_in[13];
    const float* e2 = (const float*)d_in[14];

    const int N = in_sizes[0] / 16;               // 442368

    // ---- workspace layout ----
    char* ws = (char*)d_ws;
    size_t off = 0;
    auto alloc = [&](size_t bytes) { void* p = ws + off; off = (off + bytes + 255) & ~(size_t)255; return p; };
    int*   map   = (int*)  alloc((size_t)BATCH * VOX * 4);
    float* stats = (float*)alloc(3 * 256 * 4);
    float* ss    = (float*)alloc(3 * 256 * 4);
    u16*   nbr   = (u16*)  alloc((size_t)N * 32 * 2);
    u16*   wt0   = (u16*)  alloc((size_t)64  * 448  * 2);
    u16*   wt1   = (u16*)  alloc((size_t)128 * 1728 * 2);
    u16*   wt2   = (u16*)  alloc((size_t)64  * 3456 * 2);
    u16*   fbuf  = (u16*)  alloc((size_t)BATCH * PERZ * 128 * 2);   // shared by all layers
    float* y = (float*)d_out;                     // fp32 conv out, aliases d_out

    hipMemsetAsync(map,   0xFF, (size_t)BATCH * VOX * 4, stream);
    hipMemsetAsync(stats, 0,    3 * 256 * 4, stream);
    hipMemsetAsync(wt0,   0,    (size_t)64 * 448 * 2, stream);      // zero K-pad
    build_map_kernel<<<(N + 255) / 256, 256, 0, stream>>>(idx, map, N);
    build_nbr_kernel<<<(N + 255) / 256, 256, 0, stream>>>(idx, map, nbr, N);
    transpose_w_kernel<<<(432  * 64  + 255) / 256, 256, 0, stream>>>(W0, wt0, 432,  64,  448);
    transpose_w_kernel<<<(1728 * 128 + 255) / 256, 256, 0, stream>>>(W1, wt1, 1728, 128, 1728);
    transpose_w_kernel<<<(3456 * 64  + 255) / 256, 256, 0, stream>>>(W2, wt2, 3456, 64,  3456);

    // ---- layer 1: 16 -> 64 (BM=256, waves 4x1) ----
    zero_rows_kernel<<<(BATCH * 4 + 255) / 256, 256, 0, stream>>>(fbuf, 16);
    cast_bf16_kernel<<<(N * 4 + 255) / 256, 256, 0, stream>>>(feats, fbuf, N * 4);
    conv_mfma_kernel<16, 64, 256, 4, 1><<<N / 256, 256, 0, stream>>>(fbuf, nbr, wt0, b0, y, stats + 0);
    finalize_kernel<64><<<1, 64, 0, stream>>>(stats + 0, g0, e0, ss + 0, N);
    zero_rows_kernel<<<(BATCH * 16 + 255) / 256, 256, 0, stream>>>(fbuf, 64);
    apply_kernel<64><<<(N * 16 + 255) / 256, 256, 0, stream>>>(y, ss + 0, fbuf, N * 16);

    // ---- layer 2: 64 -> 128 (BM=128, waves 2x2) ----
    conv_mfma_kernel<64, 128, 128, 2, 2><<<N / 128, 256, 0, stream>>>(fbuf, nbr, wt1, b1, y, stats + 256);
    finalize_kernel<128><<<1, 128, 0, stream>>>(stats + 256, g1, e1, ss + 256, N);
    zero_rows_kernel<<<(BATCH * 32 + 255) / 256, 256, 0, stream>>>(fbuf, 128);
    apply_kernel<128><<<(N * 32 + 255) / 256, 256, 0, stream>>>(y, ss + 256, fbuf, N * 32);

    // ---- layer 3: 128 -> 64 (BM=256, waves 4x1) ----
    conv_mfma_kernel<128, 64, 256, 4, 1><<<N / 256, 256, 0, stream>>>(fbuf, nbr, wt2, b2, y, stats + 512);
    finalize_kernel<64><<<1, 64, 0, stream>>>(stats + 512, g2, e2, ss + 512, N);
    zero_rows_kernel<<<(BATCH * 16 + 255) / 256, 256, 0, stream>>>(fbuf, 64);
    apply_kernel<64><<<(N * 16 + 255) / 256, 256, 0, stream>>>(y, ss + 512, fbuf, N * 16);

    // ---- dense NCDHW output ----
    output_kernel<<<(out_size + 255) / 256, 256, 0, stream>>>(fbuf, map, (float*)d_out, out_size);
}